// Round 2
// baseline (543.579 us; speedup 1.0000x reference)
//
#include <hip/hip_runtime.h>

// Conv2D with per-batch gumbel-sigmoid weight dropout, MI355X (gfx950).
// Strategy: prep kernel builds masked conv weights as bf16 hi/lo split
// (B-fragment layout) + masked bias; conv kernel does MFMA bf16 16x16x32
// with 3-MFMA hi/lo split for fp32-class accuracy.
//
// Geometry: B=8, H=W=512, Cin=F=32, KH=KW=3 ('SAME', stride 1).
// Conv block: 512 thr (8 waves), output tile 16x16 px x 32 F per batch.
//   wave = (rgrp 0..3 = 4 rows of 16 px) x (nh 0..1 = f-half).
//   A (LDS): input halo 18x18x32 as bf16 hi/lo, layout [kgrp][row][col][8ch].
//   B (VGPR): masked kernel frags, 9 taps x hi/lo, from ws.
//   Accum: 4 x f32x4 per wave; D layout col=lane&15, row=(lane>>4)*4+reg.

typedef unsigned short u16;
typedef unsigned int   u32;
typedef __attribute__((ext_vector_type(4))) unsigned short u16x4;
typedef __attribute__((ext_vector_type(8))) __bf16 bf16x8;
typedef __attribute__((ext_vector_type(4))) float  f32x4;

#define EPSF 1e-30f

__device__ __forceinline__ u16 f2bf(float f) {
    // round-to-nearest-even f32 -> bf16 (finite inputs only)
    u32 x = __float_as_uint(f);
    x += 0x7fffu + ((x >> 16) & 1u);
    return (u16)(x >> 16);
}
__device__ __forceinline__ float bf2f(u16 h) {
    return __uint_as_float(((u32)h) << 16);
}

// ---------------------------------------------------------------------------
// prep: masked kernel (bf16 hi/lo, B-frag layout) + masked bias
// flat < 73728: (b,tap,ci,f) conv-weight mask; next 256: (b,f) bias mask.
// ws layout: kw_hi[73728 u16] | kw_lo[73728 u16] | mbias[256 f32]
// dst index: (((b*9+t)*4 + ci/8)*32 + f)*8 + ci%8
// ---------------------------------------------------------------------------
__global__ __launch_bounds__(256) void prep_kernel(
    const float* __restrict__ kern, const float* __restrict__ bias,
    const float* __restrict__ unif_c, const float* __restrict__ unif_b,
    u16* __restrict__ kw_hi, u16* __restrict__ kw_lo,
    float* __restrict__ mbias)
{
    int flat = blockIdx.x * 256 + threadIdx.x;
    if (flat < 73728) {
        int f  = flat & 31;
        int ci = (flat >> 5) & 31;
        int t  = (flat >> 10) % 9;
        int b  = flat / 9216;
        float k = kern[flat % 9216];
        float u = unif_c[flat];
        // p_c = sigmoid(log(0.2/0.8)); 0.2/0.8 == 0.25 exactly in binary fp
        float lp = logf(0.25f);
        float p  = 1.0f / (1.0f + expf(-lp));
        float logit = logf(p + EPSF) - logf(1.0f - p + EPSF)
                    + logf(u + EPSF) - logf(1.0f - u + EPSF);
        float s  = 1.0f / (1.0f + expf(-(logit / 0.01f)));
        float w  = k * (1.0f - s);
        u16 hi = f2bf(w);
        u16 lo = f2bf(w - bf2f(hi));
        int g = ci >> 3, j = ci & 7;
        int dst = (((b * 9 + t) * 4 + g) * 32 + f) * 8 + j;
        kw_hi[dst] = hi;
        kw_lo[dst] = lo;
    } else if (flat < 73728 + 256) {
        int idx = flat - 73728;
        int f = idx & 31;
        float u = unif_b[idx];
        float logit = logf(0.2f + EPSF) - logf(0.8f + EPSF)
                    + logf(u + EPSF) - logf(1.0f - u + EPSF);
        float s = 1.0f / (1.0f + expf(-(logit / 0.01f)));
        mbias[idx] = bias[f] * (1.0f - s);
    }
}

// ---------------------------------------------------------------------------
// conv: grid (32,32,8) = (xtiles, ytiles, batch), block 512
// ---------------------------------------------------------------------------
__global__ __launch_bounds__(512) void conv_kernel(
    const float* __restrict__ in,
    const u16* __restrict__ kw_hi, const u16* __restrict__ kw_lo,
    const float* __restrict__ mbias,
    float* __restrict__ out)
{
    // LDS: input halo tile as bf16 hi/lo, [g(kgrp)][row18][col18][8ch]
    __shared__ __align__(16) u16 sAhi[4 * 18 * 18 * 8];  // 20736 B
    __shared__ __align__(16) u16 sAlo[4 * 18 * 18 * 8];  // 20736 B

    const int b    = blockIdx.z;
    const int ty0  = blockIdx.y * 16;
    const int tx0  = blockIdx.x * 16;
    const int tid  = threadIdx.x;
    const int lane = tid & 63;
    const int wave = tid >> 6;
    const int rgrp = wave & 3;   // which 4-row band of the 16-row tile
    const int nh   = wave >> 2;  // f half (0: f0-15, 1: f16-31)
    const int lm   = lane & 15;  // A row (x offset) / B col (f)
    const int g    = lane >> 4;  // k-group (channels g*8..g*8+7)

    // --- B fragments (masked kernel) straight to VGPRs (L2-resident) ---
    bf16x8 bh[9], bl[9];
    {
        const u16* ph = kw_hi + (b * 9) * 1024;
        const u16* pl = kw_lo + (b * 9) * 1024;
        const int off = (g * 32 + lm + 16 * nh) * 8;
        #pragma unroll
        for (int t = 0; t < 9; ++t) {
            bh[t] = *reinterpret_cast<const bf16x8*>(ph + t * 1024 + off);
            bl[t] = *reinterpret_cast<const bf16x8*>(pl + t * 1024 + off);
        }
    }

    // --- stage input halo 18x18x32 fp32 -> bf16 hi/lo LDS ---
    // 18*18 px * 8 float4 each = 2592 float4 loads over 512 threads
    for (int i = tid; i < 2592; i += 512) {
        int p   = i >> 3;          // pixel 0..323
        int row = p / 18;
        int col = p - row * 18;
        int c4  = (i & 7) * 4;     // channel start of this float4
        int gy  = ty0 - 1 + row;
        int gx  = tx0 - 1 + col;
        float4 v = make_float4(0.f, 0.f, 0.f, 0.f);
        if ((unsigned)gy < 512u && (unsigned)gx < 512u) {
            v = *reinterpret_cast<const float4*>(
                in + (((size_t)b * 512 + gy) * 512 + gx) * 32 + c4);
        }
        u16x4 h, l;
        h.x = f2bf(v.x); l.x = f2bf(v.x - bf2f(h.x));
        h.y = f2bf(v.y); l.y = f2bf(v.y - bf2f(h.y));
        h.z = f2bf(v.z); l.z = f2bf(v.z - bf2f(h.z));
        h.w = f2bf(v.w); l.w = f2bf(v.w - bf2f(h.w));
        int gg = c4 >> 3, j0 = c4 & 7;
        int dst = ((gg * 18 + row) * 18 + col) * 8 + j0;
        *reinterpret_cast<u16x4*>(&sAhi[dst]) = h;
        *reinterpret_cast<u16x4*>(&sAlo[dst]) = l;
    }
    __syncthreads();

    // --- main loop: 9 taps x 4 rows x 3 MFMAs ---
    f32x4 acc[4];
    #pragma unroll
    for (int r = 0; r < 4; ++r) acc[r] = (f32x4){0.f, 0.f, 0.f, 0.f};

    #pragma unroll
    for (int t = 0; t < 9; ++t) {
        const int ky = t / 3;
        const int kx = t - ky * 3;
        #pragma unroll
        for (int r = 0; r < 4; ++r) {
            const int row = rgrp * 4 + r + ky;
            const int col = lm + kx;
            const int off = ((g * 18 + row) * 18 + col) * 8;
            bf16x8 ah = *reinterpret_cast<const bf16x8*>(&sAhi[off]);
            bf16x8 al = *reinterpret_cast<const bf16x8*>(&sAlo[off]);
            acc[r] = __builtin_amdgcn_mfma_f32_16x16x32_bf16(ah, bh[t], acc[r], 0, 0, 0);
            acc[r] = __builtin_amdgcn_mfma_f32_16x16x32_bf16(al, bh[t], acc[r], 0, 0, 0);
            acc[r] = __builtin_amdgcn_mfma_f32_16x16x32_bf16(ah, bl[t], acc[r], 0, 0, 0);
        }
    }

    // --- epilogue: bias add + store ---
    const float bsv = mbias[b * 32 + lm + 16 * nh];
    #pragma unroll
    for (int r = 0; r < 4; ++r) {
        const int y = ty0 + rgrp * 4 + r;
        #pragma unroll
        for (int q = 0; q < 4; ++q) {
            const int x = tx0 + g * 4 + q;  // D row = (lane>>4)*4 + reg
            out[(((size_t)b * 512 + y) * 512 + x) * 32 + lm + 16 * nh] =
                acc[r][q] + bsv;
        }
    }
}

// ---------------------------------------------------------------------------
extern "C" void kernel_launch(void* const* d_in, const int* in_sizes, int n_in,
                              void* d_out, int out_size, void* d_ws, size_t ws_size,
                              hipStream_t stream) {
    const float* inputs = (const float*)d_in[0];
    const float* kern   = (const float*)d_in[1];
    const float* bias   = (const float*)d_in[2];
    const float* unif_c = (const float*)d_in[3];
    const float* unif_b = (const float*)d_in[4];
    float* out = (float*)d_out;

    // ws: kw_hi (147456 B) | kw_lo (147456 B) | mbias (1024 B) = 295936 B
    u16*   kw_hi = (u16*)d_ws;
    u16*   kw_lo = kw_hi + 73728;
    float* mbias = (float*)(kw_lo + 73728);

    hipLaunchKernelGGL(prep_kernel, dim3(289), dim3(256), 0, stream,
                       kern, bias, unif_c, unif_b, kw_hi, kw_lo, mbias);
    hipLaunchKernelGGL(conv_kernel, dim3(32, 32, 8), dim3(512), 0, stream,
                       inputs, kw_hi, kw_lo, mbias, out);
}

// Round 3
// 498.428 us; speedup vs baseline: 1.0906x; 1.0906x over previous
//
#include <hip/hip_runtime.h>

// Conv2D with per-batch gumbel-sigmoid weight dropout, MI355X (gfx950). v2.
// Changes vs v1 (250us, MfmaUtil 18.6%, Occ 23%, LDS-supply-bound):
//  - wave computes 3 rows x ALL 32 F: one A-read (ah,al) feeds both F-halves
//    -> per-output LDS read traffic halved (was duplicated across nh waves).
//  - B fragments streamed from global (L2-resident, 295 KB total) per tap
//    instead of 72 pinned VGPRs -> VGPR ~90, better wave supply.
//  - tile 16x24 (halo 26x18), static LDS 59.9 KB -> 2 blocks/CU (16 waves).
// Numerics unchanged: bf16 hi/lo 3-MFMA split, same per-element sum order.

typedef unsigned short u16;
typedef unsigned int   u32;
typedef __attribute__((ext_vector_type(4))) unsigned short u16x4;
typedef __attribute__((ext_vector_type(8))) __bf16 bf16x8;
typedef __attribute__((ext_vector_type(4))) float  f32x4;

#define EPSF 1e-30f

__device__ __forceinline__ u16 f2bf(float f) {
    u32 x = __float_as_uint(f);
    x += 0x7fffu + ((x >> 16) & 1u);
    return (u16)(x >> 16);
}
__device__ __forceinline__ float bf2f(u16 h) {
    return __uint_as_float(((u32)h) << 16);
}

// ---------------------------------------------------------------------------
// prep: masked kernel (bf16 hi/lo, B-frag layout) + masked bias
// dst index: (((b*9+t)*4 + ci/8)*32 + f)*8 + ci%8   (1024 u16 per (b,t))
// ws: kw_hi[73728 u16] | kw_lo[73728 u16] | mbias[256 f32]
// ---------------------------------------------------------------------------
__global__ __launch_bounds__(256) void prep_kernel(
    const float* __restrict__ kern, const float* __restrict__ bias,
    const float* __restrict__ unif_c, const float* __restrict__ unif_b,
    u16* __restrict__ kw_hi, u16* __restrict__ kw_lo,
    float* __restrict__ mbias)
{
    int flat = blockIdx.x * 256 + threadIdx.x;
    if (flat < 73728) {
        int f  = flat & 31;
        int ci = (flat >> 5) & 31;
        int t  = (flat >> 10) % 9;
        int b  = flat / 9216;
        float k = kern[flat % 9216];
        float u = unif_c[flat];
        float lp = logf(0.25f);
        float p  = 1.0f / (1.0f + expf(-lp));
        float logit = logf(p + EPSF) - logf(1.0f - p + EPSF)
                    + logf(u + EPSF) - logf(1.0f - u + EPSF);
        float s  = 1.0f / (1.0f + expf(-(logit / 0.01f)));
        float w  = k * (1.0f - s);
        u16 hi = f2bf(w);
        u16 lo = f2bf(w - bf2f(hi));
        int g = ci >> 3, j = ci & 7;
        int dst = (((b * 9 + t) * 4 + g) * 32 + f) * 8 + j;
        kw_hi[dst] = hi;
        kw_lo[dst] = lo;
    } else if (flat < 73728 + 256) {
        int idx = flat - 73728;
        int f = idx & 31;
        float u = unif_b[idx];
        float logit = logf(0.2f + EPSF) - logf(0.8f + EPSF)
                    + logf(u + EPSF) - logf(1.0f - u + EPSF);
        float s = 1.0f / (1.0f + expf(-(logit / 0.01f)));
        mbias[idx] = bias[f] * (1.0f - s);
    }
}

// ---------------------------------------------------------------------------
// conv v2: grid (32, 22, 8), block 512 (8 waves).
// Block tile: 16 x-px x 24 y-rows x 32 F. Wave w: rows w*3 .. w*3+2.
// LDS: input halo 26x18x32 bf16 hi/lo, [g][row26][col18][8ch].
// ---------------------------------------------------------------------------
#define TROWS 24
#define HROWS 26
#define ASZ (4 * HROWS * 18 * 8)   // 14976 u16 per plane

__global__ __launch_bounds__(512) void conv_kernel(
    const float* __restrict__ in,
    const u16* __restrict__ kw_hi, const u16* __restrict__ kw_lo,
    const float* __restrict__ mbias,
    float* __restrict__ out)
{
    __shared__ __align__(16) u16 sAhi[ASZ];  // 29952 B
    __shared__ __align__(16) u16 sAlo[ASZ];  // 29952 B

    const int b    = blockIdx.z;
    const int ty0  = blockIdx.y * TROWS;
    const int tx0  = blockIdx.x * 16;
    const int tid  = threadIdx.x;
    const int lane = tid & 63;
    const int wave = tid >> 6;
    const int wrow = wave * 3;   // wave's 3 output rows (tile-local)
    const int lm   = lane & 15;  // A row (x) / B col (f within half)
    const int g    = lane >> 4;  // k-chunk (channels g*8..g*8+7)

    // --- stage input halo 26x18x32 fp32 -> bf16 hi/lo LDS ---
    for (int i = tid; i < HROWS * 18 * 8; i += 512) {
        int p   = i >> 3;           // pixel 0 .. 26*18-1
        int row = p / 18;
        int col = p - row * 18;
        int c4  = (i & 7) * 4;      // channel start of this float4
        int gy  = ty0 - 1 + row;
        int gx  = tx0 - 1 + col;
        float4 v = make_float4(0.f, 0.f, 0.f, 0.f);
        if ((unsigned)gy < 512u && (unsigned)gx < 512u) {
            v = *reinterpret_cast<const float4*>(
                in + (((size_t)b * 512 + gy) * 512 + gx) * 32 + c4);
        }
        u16x4 h, l;
        h.x = f2bf(v.x); l.x = f2bf(v.x - bf2f(h.x));
        h.y = f2bf(v.y); l.y = f2bf(v.y - bf2f(h.y));
        h.z = f2bf(v.z); l.z = f2bf(v.z - bf2f(h.z));
        h.w = f2bf(v.w); l.w = f2bf(v.w - bf2f(h.w));
        int gg = c4 >> 3, j0 = c4 & 7;
        int dst = ((gg * HROWS + row) * 18 + col) * 8 + j0;
        *reinterpret_cast<u16x4*>(&sAhi[dst]) = h;
        *reinterpret_cast<u16x4*>(&sAlo[dst]) = l;
    }
    __syncthreads();

    // --- main loop: 9 taps; per tap stream 4 B-frags from L2, 3 rows x 6 MFMA
    f32x4 acc[3][2];
    #pragma unroll
    for (int r = 0; r < 3; ++r) {
        acc[r][0] = (f32x4){0.f, 0.f, 0.f, 0.f};
        acc[r][1] = (f32x4){0.f, 0.f, 0.f, 0.f};
    }

    const u16* ph = kw_hi + b * 9216;
    const u16* pl = kw_lo + b * 9216;
    const int foff0 = (g * 32 + lm) * 8;   // f = lm      (half 0)
    const int foff1 = foff0 + 128;         // f = lm + 16 (half 1)

    #pragma unroll
    for (int t = 0; t < 9; ++t) {
        const bf16x8 tbh0 = *reinterpret_cast<const bf16x8*>(ph + t * 1024 + foff0);
        const bf16x8 tbh1 = *reinterpret_cast<const bf16x8*>(ph + t * 1024 + foff1);
        const bf16x8 tbl0 = *reinterpret_cast<const bf16x8*>(pl + t * 1024 + foff0);
        const bf16x8 tbl1 = *reinterpret_cast<const bf16x8*>(pl + t * 1024 + foff1);
        const int ky = t / 3;
        const int kx = t - ky * 3;
        #pragma unroll
        for (int r = 0; r < 3; ++r) {
            const int row = wrow + r + ky;
            const int col = lm + kx;
            const int off = ((g * HROWS + row) * 18 + col) * 8;
            bf16x8 ah = *reinterpret_cast<const bf16x8*>(&sAhi[off]);
            bf16x8 al = *reinterpret_cast<const bf16x8*>(&sAlo[off]);
            // per F-half chain order identical to v1: ah*bh, al*bh, ah*bl
            acc[r][0] = __builtin_amdgcn_mfma_f32_16x16x32_bf16(ah, tbh0, acc[r][0], 0, 0, 0);
            acc[r][1] = __builtin_amdgcn_mfma_f32_16x16x32_bf16(ah, tbh1, acc[r][1], 0, 0, 0);
            acc[r][0] = __builtin_amdgcn_mfma_f32_16x16x32_bf16(al, tbh0, acc[r][0], 0, 0, 0);
            acc[r][1] = __builtin_amdgcn_mfma_f32_16x16x32_bf16(al, tbh1, acc[r][1], 0, 0, 0);
            acc[r][0] = __builtin_amdgcn_mfma_f32_16x16x32_bf16(ah, tbl0, acc[r][0], 0, 0, 0);
            acc[r][1] = __builtin_amdgcn_mfma_f32_16x16x32_bf16(ah, tbl1, acc[r][1], 0, 0, 0);
        }
    }

    // --- epilogue: bias add + store (D: col=lane&15=f, row=(lane>>4)*4+q=x) ---
    const float bsv0 = mbias[b * 32 + lm];
    const float bsv1 = mbias[b * 32 + lm + 16];
    #pragma unroll
    for (int r = 0; r < 3; ++r) {
        const int y = ty0 + wrow + r;
        if (y < 512) {
            #pragma unroll
            for (int q = 0; q < 4; ++q) {
                const int x = tx0 + g * 4 + q;
                const size_t base = (((size_t)b * 512 + y) * 512 + x) * 32;
                out[base + lm]      = acc[r][0][q] + bsv0;
                out[base + lm + 16] = acc[r][1][q] + bsv1;
            }
        }
    }
}

// ---------------------------------------------------------------------------
extern "C" void kernel_launch(void* const* d_in, const int* in_sizes, int n_in,
                              void* d_out, int out_size, void* d_ws, size_t ws_size,
                              hipStream_t stream) {
    const float* inputs = (const float*)d_in[0];
    const float* kern   = (const float*)d_in[1];
    const float* bias   = (const float*)d_in[2];
    const float* unif_c = (const float*)d_in[3];
    const float* unif_b = (const float*)d_in[4];
    float* out = (float*)d_out;

    u16*   kw_hi = (u16*)d_ws;
    u16*   kw_lo = kw_hi + 73728;
    float* mbias = (float*)(kw_lo + 73728);

    hipLaunchKernelGGL(prep_kernel, dim3(289), dim3(256), 0, stream,
                       kern, bias, unif_c, unif_b, kw_hi, kw_lo, mbias);
    hipLaunchKernelGGL(conv_kernel, dim3(32, 22, 8), dim3(512), 0, stream,
                       inputs, kw_hi, kw_lo, mbias, out);
}